// Round 4
// baseline (3405.797 us; speedup 1.0000x reference)
//
#include <hip/hip_runtime.h>
#include <cstdint>
#include <cstddef>

// Bidirectional LSTM  B=32 T=1024 D=512 H=256 (torch gate order i,f,g,o), fp32 in/out.
//
// Phase 1: xp[m][n] = sum_k x16[m][k] * W16[n][k] + bias[n]  (fp16 MFMA GEMM, xp fp16)
// Phase 2: one block per (dir,batch) chain; 256 threads; thread tid owns gate rows
//   {tid, tid+256, tid+512, tid+768} = (i,f,g,o) of output tid -> activation inline,
//   no gate exchange. Weights: 400 packed-fp16 words in regs (VGPR+AGPR via unified
//   file) + 112 words in LDS. h broadcast via 512B LDS buffer (32 uniform b128/wave).

typedef unsigned int   uint;
typedef unsigned short ushort;

constexpr int Tn = 1024;
constexpr int Bn = 32;
constexpr int Dn = 512;
constexpr int Hn = 256;
constexpr int NC = 2048;          // 2 dirs * 4H
constexpr int KT = 512;           // K of the input projection

constexpr int WR = 100;           // packed words per row in registers
constexpr int WL = 7;             // b128 chunks per row in LDS (28 words)

typedef _Float16 half8  __attribute__((ext_vector_type(8)));
typedef _Float16 half2v __attribute__((ext_vector_type(2)));
typedef float    f32x4  __attribute__((ext_vector_type(4)));

#if defined(__has_builtin)
#  if __has_builtin(__builtin_amdgcn_fdot2)
#    define HAVE_FDOT2 1
#  endif
#endif

__device__ __forceinline__ ushort f2h(float f) {
  _Float16 h = (_Float16)f;               // RNE
  return __builtin_bit_cast(ushort, h);
}
__device__ __forceinline__ float h2f(ushort s) {
  return (float)__builtin_bit_cast(_Float16, s);
}
__device__ __forceinline__ uint packh(float a, float b) {
  return (uint)f2h(a) | ((uint)f2h(b) << 16);
}

__device__ __forceinline__ float dot2h(uint w, uint h, float acc) {
#ifdef HAVE_FDOT2
  return __builtin_amdgcn_fdot2(__builtin_bit_cast(half2v, w),
                                __builtin_bit_cast(half2v, h), acc, false);
#else
  acc = fmaf(h2f((ushort)(w & 0xffff)), h2f((ushort)(h & 0xffff)), acc);
  acc = fmaf(h2f((ushort)(w >> 16)),    h2f((ushort)(h >> 16)),    acc);
  return acc;
#endif
}

__device__ __forceinline__ float sig_(float x) {
  x = fminf(fmaxf(x, -30.f), 30.f);
  return 1.f / (1.f + __expf(-x));
}
__device__ __forceinline__ float tanh_(float x) {
  x = fminf(fmaxf(x, -15.f), 15.f);
  float e = __expf(2.f * x);
  return (e - 1.f) / (e + 1.f);
}

// ---------------- prep kernels ----------------

__global__ void k_prep_a(const float* __restrict__ x, ushort* __restrict__ a16, long nquad) {
  long i4 = (long)blockIdx.x * blockDim.x + threadIdx.x;
  if (i4 >= nquad) return;
  const float4 v = ((const float4*)x)[i4];
  ushort4 o;
  o.x = f2h(v.x); o.y = f2h(v.y); o.z = f2h(v.z); o.w = f2h(v.w);
  ((ushort4*)a16)[i4] = o;
}

__global__ void k_prep_w(const float* __restrict__ wf, const float* __restrict__ wb,
                         const float* __restrict__ bf1, const float* __restrict__ bf2,
                         const float* __restrict__ bb1, const float* __restrict__ bb2,
                         ushort* __restrict__ w16, float* __restrict__ biasc) {
  long i4 = (long)blockIdx.x * blockDim.x + threadIdx.x;
  if (i4 >= (long)NC * (KT / 4)) return;
  int n = (int)(i4 >> 7);
  int k4 = (int)(i4 & 127);
  int dir = n >> 10, g = n & 1023;
  const float* w = dir ? wb : wf;
  const float4 v = ((const float4*)(w + (size_t)g * Dn))[k4];
  ushort4 o;
  o.x = f2h(v.x); o.y = f2h(v.y); o.z = f2h(v.z); o.w = f2h(v.w);
  ((ushort4*)w16)[i4] = o;
  if (k4 == 0) biasc[n] = dir ? (bb1[g] + bb2[g]) : (bf1[g] + bf2[g]);
}

__global__ void k_bad(float* __restrict__ out, int n) {
  int i = blockIdx.x * blockDim.x + threadIdx.x;
  if (i < n) out[i] = 54321.f;
}

// ---------------- phase 1: fp16 MFMA GEMM ----------------

__device__ __forceinline__ void gload_lds16(const void* g, void* l) {
  __builtin_amdgcn_global_load_lds((const __attribute__((address_space(1))) void*)g,
                                   (__attribute__((address_space(3))) void*)l, 16, 0, 0);
}

__global__ __launch_bounds__(256) void k_gemm(const ushort* __restrict__ A,
                                              const ushort* __restrict__ W,
                                              const float* __restrict__ biasc,
                                              ushort* __restrict__ xp) {
  __shared__ __align__(16) ushort As[128 * 32];
  __shared__ __align__(16) ushort Bs[128 * 32];
  const int bid = blockIdx.x;
  const int m0 = (bid >> 4) * 128;
  const int n0 = (bid & 15) * 128;
  const int tid = threadIdx.x;
  const int wid = tid >> 6, lane = tid & 63;
  const int wr = wid >> 1, wcq = wid & 1;
  const int l16 = lane & 15, lq = lane >> 4;

  f32x4 acc[4][4] = {};

  for (int kt = 0; kt < KT; kt += 32) {
    __syncthreads();
#pragma unroll
    for (int i = 0; i < 2; ++i) {
      int ch = wid * 2 + i;
      int p = ch * 64 + lane;
      int r = p >> 2, gp = p & 3;
      int gs = gp ^ ((r >> 1) & 3);
      gload_lds16(A + (size_t)(m0 + r) * KT + kt + gs * 8, (char*)As + ch * 1024);
      gload_lds16(W + (size_t)(n0 + r) * KT + kt + gs * 8, (char*)Bs + ch * 1024);
    }
    __syncthreads();

    half8 af[4], bfr[4];
#pragma unroll
    for (int mf = 0; mf < 4; ++mf) {
      int row = wr * 64 + mf * 16 + l16;
      int g = lq ^ ((row >> 1) & 3);
      af[mf] = *(const half8*)((const char*)As + row * 64 + g * 16);
    }
#pragma unroll
    for (int nf = 0; nf < 4; ++nf) {
      int row = wcq * 64 + nf * 16 + l16;
      int g = lq ^ ((row >> 1) & 3);
      bfr[nf] = *(const half8*)((const char*)Bs + row * 64 + g * 16);
    }
#pragma unroll
    for (int mf = 0; mf < 4; ++mf)
#pragma unroll
      for (int nf = 0; nf < 4; ++nf)
        acc[mf][nf] = __builtin_amdgcn_mfma_f32_16x16x32_f16(af[mf], bfr[nf], acc[mf][nf], 0, 0, 0);
  }

#pragma unroll
  for (int nf = 0; nf < 4; ++nf) {
    int col = n0 + wcq * 64 + nf * 16 + l16;
    float bv = biasc[col];
#pragma unroll
    for (int mf = 0; mf < 4; ++mf) {
      int rbase = m0 + wr * 64 + mf * 16 + lq * 4;
#pragma unroll
      for (int i = 0; i < 4; ++i)
        xp[(size_t)(rbase + i) * NC + col] = f2h(acc[mf][nf][i] + bv);
    }
  }
}

// ---------------- phase 2: one block per (dir,batch), 256 threads ----------------

__global__ __launch_bounds__(256, 1) void k_lstm(const float* __restrict__ whhF,
                                                 const float* __restrict__ whhB,
                                                 const ushort* __restrict__ xp,
                                                 float* __restrict__ out,
                                                 int b_base) {
  const int dir = blockIdx.x & 1;
  const int bl  = blockIdx.x >> 1;
  const int tid = threadIdx.x;                 // output index 0..255

  __shared__ __align__(16) uint4 wl4[4][WL][256];   // 112 KB weight tail
  __shared__ __align__(16) uint  hp32[128];         // packed fp16 h[256]

  const float* whh = dir ? whhB : whhF;

  // persistent weights: rows {tid + 256r}, words 0..WR-1 in regs, rest in LDS
  uint wreg[4 * WR];
#pragma unroll
  for (int r = 0; r < 4; ++r) {
    const float4* w4 = (const float4*)(whh + (size_t)(r * Hn + tid) * Hn);
#pragma unroll
    for (int i = 0; i < WR / 2; ++i) {
      float4 v = w4[i];
      wreg[r * WR + 2 * i]     = packh(v.x, v.y);
      wreg[r * WR + 2 * i + 1] = packh(v.z, v.w);
    }
#pragma unroll
    for (int c = 0; c < WL; ++c) {
      float4 a = w4[WR / 2 + 2 * c], b = w4[WR / 2 + 2 * c + 1];
      wl4[r][c][tid] = (uint4){ packh(a.x, a.y), packh(a.z, a.w),
                                packh(b.x, b.y), packh(b.z, b.w) };
    }
  }
  if (tid < 128) hp32[tid] = 0;                // h_{-1} = 0
  float creg = 0.f;
  __syncthreads();

  const int dstep = dir ? -1 : 1;
  int tphys = dir ? (Tn - 1) : 0;
  const ptrdiff_t xstr = (ptrdiff_t)dstep * NC;
  const ptrdiff_t ostr = (ptrdiff_t)dstep * 512;
  const ushort* pxp = xp + (size_t)(bl * Tn + tphys) * NC + dir * 1024 + tid;
  float* pout = out + (size_t)((b_base + bl) * Tn + tphys) * 512 + dir * 256 + tid;
  ushort xq0 = pxp[0], xq1 = pxp[256], xq2 = pxp[512], xq3 = pxp[768];

  const uint4* hp4 = (const uint4*)hp32;

#pragma unroll 1
  for (int t = 0; t < Tn; ++t) {
    float a0 = h2f(xq0), a1 = h2f(xq1), a2 = h2f(xq2), a3 = h2f(xq3);
    if (t + 1 < Tn) {                          // prefetch next step's xp
      pxp += xstr;
      xq0 = pxp[0]; xq1 = pxp[256]; xq2 = pxp[512]; xq3 = pxp[768];
    }

#pragma unroll
    for (int q = 0; q < WR / 4; ++q) {         // k-words 0..WR-1 (register weights)
      uint4 h4 = hp4[q];
      a0 = dot2h(wreg[0 * WR + 4 * q + 0], h4.x, a0);
      a1 = dot2h(wreg[1 * WR + 4 * q + 0], h4.x, a1);
      a2 = dot2h(wreg[2 * WR + 4 * q + 0], h4.x, a2);
      a3 = dot2h(wreg[3 * WR + 4 * q + 0], h4.x, a3);
      a0 = dot2h(wreg[0 * WR + 4 * q + 1], h4.y, a0);
      a1 = dot2h(wreg[1 * WR + 4 * q + 1], h4.y, a1);
      a2 = dot2h(wreg[2 * WR + 4 * q + 1], h4.y, a2);
      a3 = dot2h(wreg[3 * WR + 4 * q + 1], h4.y, a3);
      a0 = dot2h(wreg[0 * WR + 4 * q + 2], h4.z, a0);
      a1 = dot2h(wreg[1 * WR + 4 * q + 2], h4.z, a1);
      a2 = dot2h(wreg[2 * WR + 4 * q + 2], h4.z, a2);
      a3 = dot2h(wreg[3 * WR + 4 * q + 2], h4.z, a3);
      a0 = dot2h(wreg[0 * WR + 4 * q + 3], h4.w, a0);
      a1 = dot2h(wreg[1 * WR + 4 * q + 3], h4.w, a1);
      a2 = dot2h(wreg[2 * WR + 4 * q + 3], h4.w, a2);
      a3 = dot2h(wreg[3 * WR + 4 * q + 3], h4.w, a3);
    }
#pragma unroll
    for (int c = 0; c < WL; ++c) {             // k-words WR.. (LDS weights)
      uint4 w0 = wl4[0][c][tid];
      uint4 w1 = wl4[1][c][tid];
      uint4 w2 = wl4[2][c][tid];
      uint4 w3 = wl4[3][c][tid];
      uint4 h4 = hp4[WR / 4 + c];
      a0 = dot2h(w0.x, h4.x, a0);
      a1 = dot2h(w1.x, h4.x, a1);
      a2 = dot2h(w2.x, h4.x, a2);
      a3 = dot2h(w3.x, h4.x, a3);
      a0 = dot2h(w0.y, h4.y, a0);
      a1 = dot2h(w1.y, h4.y, a1);
      a2 = dot2h(w2.y, h4.y, a2);
      a3 = dot2h(w3.y, h4.y, a3);
      a0 = dot2h(w0.z, h4.z, a0);
      a1 = dot2h(w1.z, h4.z, a1);
      a2 = dot2h(w2.z, h4.z, a2);
      a3 = dot2h(w3.z, h4.z, a3);
      a0 = dot2h(w0.w, h4.w, a0);
      a1 = dot2h(w1.w, h4.w, a1);
      a2 = dot2h(w2.w, h4.w, a2);
      a3 = dot2h(w3.w, h4.w, a3);
    }

    // activation (all 256 threads, no divergence); gates stay fp32
    float iv = sig_(a0), fv = sig_(a1), gv = tanh_(a2), ov = sig_(a3);
    float cc = fv * creg + iv * gv;
    creg = cc;
    float h = ov * tanh_(cc);
    *pout = h;
    pout += ostr;

    __syncthreads();                            // all reads of old h done
    ((ushort*)hp32)[tid] = f2h(h);
    __syncthreads();                            // new h visible
    tphys += dstep;
  }
  (void)tphys;
}

// ---------------- host ----------------

extern "C" void kernel_launch(void* const* d_in, const int* in_sizes, int n_in,
                              void* d_out, int out_size, void* d_ws, size_t ws_size,
                              hipStream_t stream) {
  const float* x     = (const float*)d_in[0];
  const float* Wih_f = (const float*)d_in[1];
  const float* Whh_f = (const float*)d_in[2];
  const float* bih_f = (const float*)d_in[3];
  const float* bhh_f = (const float*)d_in[4];
  const float* Wih_b = (const float*)d_in[5];
  const float* Whh_b = (const float*)d_in[6];
  const float* bib_b = (const float*)d_in[7];
  const float* bhh_b = (const float*)d_in[8];
  float* out = (float*)d_out;

  const size_t szW16  = (size_t)NC * KT * 2;        // 2 MiB
  const size_t szBias = (size_t)NC * 4;

  int c = 0;
  size_t szA16 = 0, szXp = 0;
  for (int cc = 1; cc <= 16; cc *= 2) {
    size_t a = (size_t)(Bn / cc) * Tn * KT * 2;
    size_t p = (size_t)(Bn / cc) * Tn * NC * 2;
    if (szW16 + szBias + a + p <= ws_size) { c = cc; szA16 = a; szXp = p; break; }
  }
  if (c == 0) {
    k_bad<<<(out_size + 255) / 256, 256, 0, stream>>>(out, out_size);
    return;
  }

  char* ws = (char*)d_ws;
  ushort* W16   = (ushort*)ws;
  float*  biasc = (float*)(ws + szW16);
  ushort* A16   = (ushort*)(ws + szW16 + szBias);
  ushort* xp    = (ushort*)(ws + szW16 + szBias + szA16);

  {
    long n4 = (long)NC * (KT / 4);
    k_prep_w<<<(int)((n4 + 255) / 256), 256, 0, stream>>>(Wih_f, Wih_b, bih_f, bhh_f,
                                                          bib_b, bhh_b, W16, biasc);
  }

  const int sizeB = Bn / c;
  for (int cb = 0; cb < c; ++cb) {
    const int b_base = cb * sizeB;
    {
      long nquad = (long)sizeB * Tn * KT / 4;
      k_prep_a<<<(int)((nquad + 255) / 256), 256, 0, stream>>>(
          x + (size_t)b_base * Tn * Dn, A16, nquad);
    }
    k_gemm<<<dim3(sizeB * 8 * 16), dim3(256), 0, stream>>>(A16, W16, biasc, xp);
    k_lstm<<<dim3(2 * sizeB), dim3(256), 0, stream>>>(Whh_f, Whh_b, xp, out, b_base);
  }
}

// Round 5
// 2146.972 us; speedup vs baseline: 1.5863x; 1.5863x over previous
//
#include <hip/hip_runtime.h>
#include <cstdint>
#include <cstddef>

// Bidirectional LSTM  B=32 T=1024 D=512 H=256 (torch gate order i,f,g,o), fp32 in/out.
//
// Phase 1: xp[m][n] = sum_k x16[m][k] * W16[n][k] + bias[n]  (fp16 MFMA GEMM, xp fp16)
// Phase 2: one block per (dir,batch) chain; 512 threads (8 waves, 2/SIMD).
//   Thread tid owns gate rows {tid, tid+512}: tid<256 -> (i,g) of output tid;
//   tid>=256 -> (f,o) of output tid-256. Weights: 224 packed-fp16 words in VGPRs
//   (row0 full 128, row1 first 96) + row1 tail 32 words in LDS (8 x b128).
//   h broadcast via 512B LDS; (f,o) handed over via 2KB LDS; c stays in regs of
//   threads 0..255. Per step: 512 v_dot2_f32_f16 per thread-pair, 2 barriers.

typedef unsigned int   uint;
typedef unsigned short ushort;

constexpr int Tn = 1024;
constexpr int Bn = 32;
constexpr int Dn = 512;
constexpr int Hn = 256;
constexpr int NC = 2048;          // 2 dirs * 4H
constexpr int KT = 512;           // K of the input projection

typedef _Float16 half8  __attribute__((ext_vector_type(8)));
typedef _Float16 half2v __attribute__((ext_vector_type(2)));
typedef float    f32x4  __attribute__((ext_vector_type(4)));

#if defined(__has_builtin)
#  if __has_builtin(__builtin_amdgcn_fdot2)
#    define HAVE_FDOT2 1
#  endif
#endif

__device__ __forceinline__ ushort f2h(float f) {
  _Float16 h = (_Float16)f;               // RNE
  return __builtin_bit_cast(ushort, h);
}
__device__ __forceinline__ float h2f(ushort s) {
  return (float)__builtin_bit_cast(_Float16, s);
}
__device__ __forceinline__ uint packh(float a, float b) {
  return (uint)f2h(a) | ((uint)f2h(b) << 16);
}

__device__ __forceinline__ float dot2h(uint w, uint h, float acc) {
#ifdef HAVE_FDOT2
  return __builtin_amdgcn_fdot2(__builtin_bit_cast(half2v, w),
                                __builtin_bit_cast(half2v, h), acc, false);
#else
  acc = fmaf(h2f((ushort)(w & 0xffff)), h2f((ushort)(h & 0xffff)), acc);
  acc = fmaf(h2f((ushort)(w >> 16)),    h2f((ushort)(h >> 16)),    acc);
  return acc;
#endif
}

__device__ __forceinline__ float sig_(float x) {
  x = fminf(fmaxf(x, -30.f), 30.f);
  return 1.f / (1.f + __expf(-x));
}
__device__ __forceinline__ float tanh_(float x) {
  x = fminf(fmaxf(x, -15.f), 15.f);
  float e = __expf(2.f * x);
  return (e - 1.f) / (e + 1.f);
}

// ---------------- prep kernels ----------------

__global__ void k_prep_a(const float* __restrict__ x, ushort* __restrict__ a16, long nquad) {
  long i4 = (long)blockIdx.x * blockDim.x + threadIdx.x;
  if (i4 >= nquad) return;
  const float4 v = ((const float4*)x)[i4];
  ushort4 o;
  o.x = f2h(v.x); o.y = f2h(v.y); o.z = f2h(v.z); o.w = f2h(v.w);
  ((ushort4*)a16)[i4] = o;
}

__global__ void k_prep_w(const float* __restrict__ wf, const float* __restrict__ wb,
                         const float* __restrict__ bf1, const float* __restrict__ bf2,
                         const float* __restrict__ bb1, const float* __restrict__ bb2,
                         ushort* __restrict__ w16, float* __restrict__ biasc) {
  long i4 = (long)blockIdx.x * blockDim.x + threadIdx.x;
  if (i4 >= (long)NC * (KT / 4)) return;
  int n = (int)(i4 >> 7);
  int k4 = (int)(i4 & 127);
  int dir = n >> 10, g = n & 1023;
  const float* w = dir ? wb : wf;
  const float4 v = ((const float4*)(w + (size_t)g * Dn))[k4];
  ushort4 o;
  o.x = f2h(v.x); o.y = f2h(v.y); o.z = f2h(v.z); o.w = f2h(v.w);
  ((ushort4*)w16)[i4] = o;
  if (k4 == 0) biasc[n] = dir ? (bb1[g] + bb2[g]) : (bf1[g] + bf2[g]);
}

__global__ void k_bad(float* __restrict__ out, int n) {
  int i = blockIdx.x * blockDim.x + threadIdx.x;
  if (i < n) out[i] = 54321.f;
}

// ---------------- phase 1: fp16 MFMA GEMM ----------------

__device__ __forceinline__ void gload_lds16(const void* g, void* l) {
  __builtin_amdgcn_global_load_lds((const __attribute__((address_space(1))) void*)g,
                                   (__attribute__((address_space(3))) void*)l, 16, 0, 0);
}

__global__ __launch_bounds__(256) void k_gemm(const ushort* __restrict__ A,
                                              const ushort* __restrict__ W,
                                              const float* __restrict__ biasc,
                                              ushort* __restrict__ xp) {
  __shared__ __align__(16) ushort As[128 * 32];
  __shared__ __align__(16) ushort Bs[128 * 32];
  const int bid = blockIdx.x;
  const int m0 = (bid >> 4) * 128;
  const int n0 = (bid & 15) * 128;
  const int tid = threadIdx.x;
  const int wid = tid >> 6, lane = tid & 63;
  const int wr = wid >> 1, wcq = wid & 1;
  const int l16 = lane & 15, lq = lane >> 4;

  f32x4 acc[4][4] = {};

  for (int kt = 0; kt < KT; kt += 32) {
    __syncthreads();
#pragma unroll
    for (int i = 0; i < 2; ++i) {
      int ch = wid * 2 + i;
      int p = ch * 64 + lane;
      int r = p >> 2, gp = p & 3;
      int gs = gp ^ ((r >> 1) & 3);
      gload_lds16(A + (size_t)(m0 + r) * KT + kt + gs * 8, (char*)As + ch * 1024);
      gload_lds16(W + (size_t)(n0 + r) * KT + kt + gs * 8, (char*)Bs + ch * 1024);
    }
    __syncthreads();

    half8 af[4], bfr[4];
#pragma unroll
    for (int mf = 0; mf < 4; ++mf) {
      int row = wr * 64 + mf * 16 + l16;
      int g = lq ^ ((row >> 1) & 3);
      af[mf] = *(const half8*)((const char*)As + row * 64 + g * 16);
    }
#pragma unroll
    for (int nf = 0; nf < 4; ++nf) {
      int row = wcq * 64 + nf * 16 + l16;
      int g = lq ^ ((row >> 1) & 3);
      bfr[nf] = *(const half8*)((const char*)Bs + row * 64 + g * 16);
    }
#pragma unroll
    for (int mf = 0; mf < 4; ++mf)
#pragma unroll
      for (int nf = 0; nf < 4; ++nf)
        acc[mf][nf] = __builtin_amdgcn_mfma_f32_16x16x32_f16(af[mf], bfr[nf], acc[mf][nf], 0, 0, 0);
  }

#pragma unroll
  for (int nf = 0; nf < 4; ++nf) {
    int col = n0 + wcq * 64 + nf * 16 + l16;
    float bv = biasc[col];
#pragma unroll
    for (int mf = 0; mf < 4; ++mf) {
      int rbase = m0 + wr * 64 + mf * 16 + lq * 4;
#pragma unroll
      for (int i = 0; i < 4; ++i)
        xp[(size_t)(rbase + i) * NC + col] = f2h(acc[mf][nf][i] + bv);
    }
  }
}

// ---------------- phase 2: one block per (dir,batch), 512 threads ----------------

__global__ __launch_bounds__(512, 2) void k_lstm(const float* __restrict__ whhF,
                                                 const float* __restrict__ whhB,
                                                 const ushort* __restrict__ xp,
                                                 float* __restrict__ out,
                                                 int b_base) {
  const int dir = blockIdx.x & 1;
  const int bl  = blockIdx.x >> 1;
  const int tid = threadIdx.x;                 // 0..511

  __shared__ __align__(16) uint4 wl[8][512];   // row1 weight tail (64 KB)
  __shared__ __align__(16) uint  hp32[128];    // packed fp16 h[256]
  __shared__ float gfo[2][256];                // (f,o) handoff

  const float* whh = dir ? whhB : whhF;

  // persistent weights: row0 = tid (words 0..127 in regs), row1 = tid+512
  // (words 0..95 in regs, words 96..127 in LDS as 8 x uint4)
  uint w0[128], w1[96];
  {
    const float4* w4 = (const float4*)(whh + (size_t)tid * Hn);
#pragma unroll
    for (int i = 0; i < 64; ++i) {
      float4 v = w4[i];
      w0[2 * i]     = packh(v.x, v.y);
      w0[2 * i + 1] = packh(v.z, v.w);
    }
    const float4* w4b = (const float4*)(whh + (size_t)(512 + tid) * Hn);
#pragma unroll
    for (int i = 0; i < 48; ++i) {
      float4 v = w4b[i];
      w1[2 * i]     = packh(v.x, v.y);
      w1[2 * i + 1] = packh(v.z, v.w);
    }
#pragma unroll
    for (int c = 0; c < 8; ++c) {
      float4 a = w4b[48 + 2 * c], b = w4b[49 + 2 * c];
      wl[c][tid] = (uint4){ packh(a.x, a.y), packh(a.z, a.w),
                            packh(b.x, b.y), packh(b.z, b.w) };
    }
  }
  if (tid < 128) hp32[tid] = 0;                // h_{-1} = 0
  float creg = 0.f;                            // c for output tid (threads 0..255)
  __syncthreads();

  const int dstep = dir ? -1 : 1;
  int tphys = dir ? (Tn - 1) : 0;
  const ptrdiff_t xstr = (ptrdiff_t)dstep * NC;
  const ptrdiff_t ostr = (ptrdiff_t)dstep * 512;
  const ushort* pxp = xp + (size_t)(bl * Tn + tphys) * NC + dir * 1024 + tid;
  float* pout = out + (size_t)((b_base + bl) * Tn + tphys) * 512 + dir * 256 + (tid & 255);
  ushort xq0 = pxp[0], xq1 = pxp[512];

  const uint4* hp4 = (const uint4*)hp32;

#pragma unroll 1
  for (int t = 0; t < Tn; ++t) {
    // 8 independent accumulator chains (4 per row, one per uint4 component)
    float a0c0 = h2f(xq0), a0c1 = 0.f, a0c2 = 0.f, a0c3 = 0.f;
    float a1c0 = h2f(xq1), a1c1 = 0.f, a1c2 = 0.f, a1c3 = 0.f;
    if (t + 1 < Tn) { pxp += xstr; xq0 = pxp[0]; xq1 = pxp[512]; }

#pragma unroll
    for (int q = 0; q < 24; ++q) {             // both rows from VGPR
      uint4 h4 = hp4[q];
      a0c0 = dot2h(w0[4 * q + 0], h4.x, a0c0);
      a0c1 = dot2h(w0[4 * q + 1], h4.y, a0c1);
      a0c2 = dot2h(w0[4 * q + 2], h4.z, a0c2);
      a0c3 = dot2h(w0[4 * q + 3], h4.w, a0c3);
      a1c0 = dot2h(w1[4 * q + 0], h4.x, a1c0);
      a1c1 = dot2h(w1[4 * q + 1], h4.y, a1c1);
      a1c2 = dot2h(w1[4 * q + 2], h4.z, a1c2);
      a1c3 = dot2h(w1[4 * q + 3], h4.w, a1c3);
    }
#pragma unroll
    for (int q = 24; q < 32; ++q) {            // row0 VGPR, row1 LDS tail
      uint4 h4 = hp4[q];
      uint4 wt = wl[q - 24][tid];
      a0c0 = dot2h(w0[4 * q + 0], h4.x, a0c0);
      a0c1 = dot2h(w0[4 * q + 1], h4.y, a0c1);
      a0c2 = dot2h(w0[4 * q + 2], h4.z, a0c2);
      a0c3 = dot2h(w0[4 * q + 3], h4.w, a0c3);
      a1c0 = dot2h(wt.x, h4.x, a1c0);
      a1c1 = dot2h(wt.y, h4.y, a1c1);
      a1c2 = dot2h(wt.z, h4.z, a1c2);
      a1c3 = dot2h(wt.w, h4.w, a1c3);
    }
    float a0 = (a0c0 + a0c1) + (a0c2 + a0c3);  // row tid      (i or f)
    float a1 = (a1c0 + a1c1) + (a1c2 + a1c3);  // row tid+512  (g or o)

    if (tid >= 256) {                          // hand (f,o) to the paired thread
      gfo[0][tid - 256] = a0;
      gfo[1][tid - 256] = a1;
    }
    __syncthreads();
    if (tid < 256) {
      float iv = sig_(a0), gv = tanh_(a1);
      float fv = sig_(gfo[0][tid]), ov = sig_(gfo[1][tid]);
      float cc = fv * creg + iv * gv;
      creg = cc;
      float h = ov * tanh_(cc);
      *pout = h;
      ((ushort*)hp32)[tid] = f2h(h);
    }
    pout += ostr;
    __syncthreads();
    tphys += dstep;
  }
  (void)tphys;
}

// ---------------- host ----------------

extern "C" void kernel_launch(void* const* d_in, const int* in_sizes, int n_in,
                              void* d_out, int out_size, void* d_ws, size_t ws_size,
                              hipStream_t stream) {
  const float* x     = (const float*)d_in[0];
  const float* Wih_f = (const float*)d_in[1];
  const float* Whh_f = (const float*)d_in[2];
  const float* bih_f = (const float*)d_in[3];
  const float* bhh_f = (const float*)d_in[4];
  const float* Wih_b = (const float*)d_in[5];
  const float* Whh_b = (const float*)d_in[6];
  const float* bib_b = (const float*)d_in[7];
  const float* bhh_b = (const float*)d_in[8];
  float* out = (float*)d_out;

  const size_t szW16  = (size_t)NC * KT * 2;        // 2 MiB
  const size_t szBias = (size_t)NC * 4;

  int c = 0;
  size_t szA16 = 0, szXp = 0;
  for (int cc = 1; cc <= 16; cc *= 2) {
    size_t a = (size_t)(Bn / cc) * Tn * KT * 2;
    size_t p = (size_t)(Bn / cc) * Tn * NC * 2;
    if (szW16 + szBias + a + p <= ws_size) { c = cc; szA16 = a; szXp = p; break; }
  }
  if (c == 0) {
    k_bad<<<(out_size + 255) / 256, 256, 0, stream>>>(out, out_size);
    return;
  }

  char* ws = (char*)d_ws;
  ushort* W16   = (ushort*)ws;
  float*  biasc = (float*)(ws + szW16);
  ushort* A16   = (ushort*)(ws + szW16 + szBias);
  ushort* xp    = (ushort*)(ws + szW16 + szBias + szA16);

  {
    long n4 = (long)NC * (KT / 4);
    k_prep_w<<<(int)((n4 + 255) / 256), 256, 0, stream>>>(Wih_f, Wih_b, bih_f, bhh_f,
                                                          bib_b, bhh_b, W16, biasc);
  }

  const int sizeB = Bn / c;
  for (int cb = 0; cb < c; ++cb) {
    const int b_base = cb * sizeB;
    {
      long nquad = (long)sizeB * Tn * KT / 4;
      k_prep_a<<<(int)((nquad + 255) / 256), 256, 0, stream>>>(
          x + (size_t)b_base * Tn * Dn, A16, nquad);
    }
    k_gemm<<<dim3(sizeB * 8 * 16), dim3(256), 0, stream>>>(A16, W16, biasc, xp);
    k_lstm<<<dim3(2 * sizeB), dim3(512), 0, stream>>>(Whh_f, Whh_b, xp, out, b_base);
  }
}

// Round 6
// 2077.428 us; speedup vs baseline: 1.6394x; 1.0335x over previous
//
#include <hip/hip_runtime.h>
#include <cstdint>
#include <cstddef>

// Bidirectional LSTM  B=32 T=1024 D=512 H=256 (torch gate order i,f,g,o), fp32 in/out.
//
// Phase 1: xp[m][n] = sum_k x16[m][k] * W16[n][k] + bias[n]  (fp16 MFMA GEMM, xp fp16)
// Phase 2: MFMA recurrence. One block per (dir,batch) chain, 512 threads (8 waves).
//   Wave w owns outputs [32w,32w+32): M-tiles {g*16+2w+j} for g=0..3 (i,f,g,o), j=0..1.
//   64 A-frags (16x16x32 fp16) per wave: 40 in VGPRs, 15 in LDS, 9 re-read from L2
//   each step (frag buffer WF shared by all blocks of a dir -> L2-resident).
//   B-frag: every lane loads the same h chunk (col-redundant) -> all D cols valid.
//   gates = D + xp (acc starts 0, xp loaded scalar per-output). Activation
//   one-output-per-lane via 4KB LDS bounce. One barrier per step.

typedef unsigned int   uint;
typedef unsigned short ushort;

constexpr int Tn = 1024;
constexpr int Bn = 32;
constexpr int Dn = 512;
constexpr int Hn = 256;
constexpr int NC = 2048;          // 2 dirs * 4H
constexpr int KT = 512;           // K of the input projection

constexpr int AR = 40;            // reg-resident A frags per wave (kt 0..4)
constexpr int ALN = 15;           // LDS-resident A frags per wave (kt5 mt0-7, kt6 mt0-6)
constexpr int GLN = 9;            // L2-resident A frags per wave (kt6 mt7, kt7 mt0-7)

typedef _Float16 half8  __attribute__((ext_vector_type(8)));
typedef float    f32x4  __attribute__((ext_vector_type(4)));

__device__ __forceinline__ ushort f2h(float f) {
  _Float16 h = (_Float16)f;               // RNE
  return __builtin_bit_cast(ushort, h);
}
__device__ __forceinline__ float h2f(ushort s) {
  return (float)__builtin_bit_cast(_Float16, s);
}
__device__ __forceinline__ uint packh(float a, float b) {
  return (uint)f2h(a) | ((uint)f2h(b) << 16);
}
__device__ __forceinline__ f32x4 mf(uint4 a, uint4 b, f32x4 c) {
  return __builtin_amdgcn_mfma_f32_16x16x32_f16(
      __builtin_bit_cast(half8, a), __builtin_bit_cast(half8, b), c, 0, 0, 0);
}

__device__ __forceinline__ float sig_(float x) {
  x = fminf(fmaxf(x, -30.f), 30.f);
  return 1.f / (1.f + __expf(-x));
}
__device__ __forceinline__ float tanh_(float x) {
  x = fminf(fmaxf(x, -15.f), 15.f);
  float e = __expf(2.f * x);
  return (e - 1.f) / (e + 1.f);
}

// ---------------- prep kernels ----------------

__global__ void k_prep_a(const float* __restrict__ x, ushort* __restrict__ a16, long nquad) {
  long i4 = (long)blockIdx.x * blockDim.x + threadIdx.x;
  if (i4 >= nquad) return;
  const float4 v = ((const float4*)x)[i4];
  ushort4 o;
  o.x = f2h(v.x); o.y = f2h(v.y); o.z = f2h(v.z); o.w = f2h(v.w);
  ((ushort4*)a16)[i4] = o;
}

__global__ void k_prep_w(const float* __restrict__ wf, const float* __restrict__ wb,
                         const float* __restrict__ bf1, const float* __restrict__ bf2,
                         const float* __restrict__ bb1, const float* __restrict__ bb2,
                         ushort* __restrict__ w16, float* __restrict__ biasc) {
  long i4 = (long)blockIdx.x * blockDim.x + threadIdx.x;
  if (i4 >= (long)NC * (KT / 4)) return;
  int n = (int)(i4 >> 7);
  int k4 = (int)(i4 & 127);
  int dir = n >> 10, g = n & 1023;
  const float* w = dir ? wb : wf;
  const float4 v = ((const float4*)(w + (size_t)g * Dn))[k4];
  ushort4 o;
  o.x = f2h(v.x); o.y = f2h(v.y); o.z = f2h(v.z); o.w = f2h(v.w);
  ((ushort4*)w16)[i4] = o;
  if (k4 == 0) biasc[n] = dir ? (bb1[g] + bb2[g]) : (bf1[g] + bf2[g]);
}

// Whh -> MFMA A-fragment layout. WF[dir][wave][fidx][lane] (uint4 = half8).
// fidx = kt*8 + (g*2+j); tile = g*16 + 2*w + j; row = tile*16 + (lane&15);
// k = kt*32 + (lane>>4)*8 .. +7.
__global__ void k_prep_whh(const float* __restrict__ whhF, const float* __restrict__ whhB,
                           uint4* __restrict__ WF) {
  int t = blockIdx.x * blockDim.x + threadIdx.x;   // 0 .. 2*8*64*64-1
  if (t >= 2 * 8 * 64 * 64) return;
  int lane = t & 63;
  int fidx = (t >> 6) & 63;
  int w    = (t >> 12) & 7;
  int dir  = t >> 15;
  int kt = fidx >> 3, mi = fidx & 7;
  int g = mi >> 1, j = mi & 1;
  int row = (g * 16 + 2 * w + j) * 16 + (lane & 15);
  int kb  = kt * 32 + (lane >> 4) * 8;
  const float* whh = dir ? whhB : whhF;
  const float4* s = (const float4*)(whh + (size_t)row * Hn + kb);
  float4 v0 = s[0], v1 = s[1];
  WF[t] = (uint4){ packh(v0.x, v0.y), packh(v0.z, v0.w),
                   packh(v1.x, v1.y), packh(v1.z, v1.w) };
}

__global__ void k_bad(float* __restrict__ out, int n) {
  int i = blockIdx.x * blockDim.x + threadIdx.x;
  if (i < n) out[i] = 54321.f;
}

// ---------------- phase 1: fp16 MFMA GEMM ----------------

__device__ __forceinline__ void gload_lds16(const void* g, void* l) {
  __builtin_amdgcn_global_load_lds((const __attribute__((address_space(1))) void*)g,
                                   (__attribute__((address_space(3))) void*)l, 16, 0, 0);
}

__global__ __launch_bounds__(256) void k_gemm(const ushort* __restrict__ A,
                                              const ushort* __restrict__ W,
                                              const float* __restrict__ biasc,
                                              ushort* __restrict__ xp) {
  __shared__ __align__(16) ushort As[128 * 32];
  __shared__ __align__(16) ushort Bs[128 * 32];
  const int bid = blockIdx.x;
  const int m0 = (bid >> 4) * 128;
  const int n0 = (bid & 15) * 128;
  const int tid = threadIdx.x;
  const int wid = tid >> 6, lane = tid & 63;
  const int wr = wid >> 1, wcq = wid & 1;
  const int l16 = lane & 15, lq = lane >> 4;

  f32x4 acc[4][4] = {};

  for (int kt = 0; kt < KT; kt += 32) {
    __syncthreads();
#pragma unroll
    for (int i = 0; i < 2; ++i) {
      int ch = wid * 2 + i;
      int p = ch * 64 + lane;
      int r = p >> 2, gp = p & 3;
      int gs = gp ^ ((r >> 1) & 3);
      gload_lds16(A + (size_t)(m0 + r) * KT + kt + gs * 8, (char*)As + ch * 1024);
      gload_lds16(W + (size_t)(n0 + r) * KT + kt + gs * 8, (char*)Bs + ch * 1024);
    }
    __syncthreads();

    half8 af[4], bfr[4];
#pragma unroll
    for (int mfi = 0; mfi < 4; ++mfi) {
      int row = wr * 64 + mfi * 16 + l16;
      int g = lq ^ ((row >> 1) & 3);
      af[mfi] = *(const half8*)((const char*)As + row * 64 + g * 16);
    }
#pragma unroll
    for (int nf = 0; nf < 4; ++nf) {
      int row = wcq * 64 + nf * 16 + l16;
      int g = lq ^ ((row >> 1) & 3);
      bfr[nf] = *(const half8*)((const char*)Bs + row * 64 + g * 16);
    }
#pragma unroll
    for (int mfi = 0; mfi < 4; ++mfi)
#pragma unroll
      for (int nf = 0; nf < 4; ++nf)
        acc[mfi][nf] = __builtin_amdgcn_mfma_f32_16x16x32_f16(af[mfi], bfr[nf], acc[mfi][nf], 0, 0, 0);
  }

#pragma unroll
  for (int nf = 0; nf < 4; ++nf) {
    int col = n0 + wcq * 64 + nf * 16 + l16;
    float bv = biasc[col];
#pragma unroll
    for (int mfi = 0; mfi < 4; ++mfi) {
      int rbase = m0 + wr * 64 + mfi * 16 + lq * 4;
#pragma unroll
      for (int i = 0; i < 4; ++i)
        xp[(size_t)(rbase + i) * NC + col] = f2h(acc[mfi][nf][i] + bv);
    }
  }
}

// ---------------- phase 2: MFMA recurrence ----------------

__global__ __launch_bounds__(512, 2) void k_lstm(const uint4* __restrict__ WF,
                                                 const ushort* __restrict__ xp,
                                                 float* __restrict__ out,
                                                 int b_base) {
  const int dir = blockIdx.x & 1;
  const int bl  = blockIdx.x >> 1;
  const int tid = threadIdx.x;
  const int w    = tid >> 6;
  const int lane = tid & 63;
  const int lq   = lane >> 4;      // k-chunk / row-quad
  const int n    = lane & 31;      // this lane's output within the wave (2x redundant)

  __shared__ __align__(16) uint4  AL[8][ALN][64];   // 120 KB LDS A-frags
  __shared__ float  gbuf[8][128];                   // 4 KB gate bounce
  __shared__ ushort hp[2][256];                     // 1 KB h double buffer

  // ---- persistent weights ----
  const uint4* wfb = WF + (size_t)((dir * 8 + w) * 64) * 64 + lane;
  uint4 wA[AR];
#pragma unroll
  for (int f = 0; f < AR; ++f) wA[f] = wfb[(size_t)f * 64];
#pragma unroll
  for (int s = 0; s < ALN; ++s) AL[w][s][lane] = wfb[(size_t)(AR + s) * 64];
  const uint4* gwp = wfb + (size_t)(AR + ALN) * 64;

  if (tid < 256) { hp[0][tid] = 0; hp[1][tid] = 0; }
  float creg = 0.f;
  __syncthreads();

  const int dstep = dir ? -1 : 1;
  int tphys = dir ? (Tn - 1) : 0;
  const ptrdiff_t xstr = (ptrdiff_t)dstep * NC;
  const ptrdiff_t ostr = (ptrdiff_t)dstep * 512;
  const ushort* px = xp + (size_t)(bl * Tn + tphys) * NC + dir * 1024 + 32 * w + n;
  float* pout = out + (size_t)((b_base + bl) * Tn + tphys) * 512 + dir * 256 + 32 * w + n;

#pragma unroll 1
  for (int t = 0; t < Tn; ++t) {
    const int cur = t & 1;
    // xp for this lane's output (consumed at step end; latency hidden under MFMA)
    ushort xg0 = px[0], xg1 = px[256], xg2 = px[512], xg3 = px[768];
    if (t + 1 < Tn) px += xstr;

    f32x4 acc[4][2];
#pragma unroll
    for (int g = 0; g < 4; ++g)
#pragma unroll
      for (int j = 0; j < 2; ++j) acc[g][j] = (f32x4){0.f, 0.f, 0.f, 0.f};

    // B phase 1: kt 0..3 (every lane loads the same h chunk -> all cols equal)
    uint4 b[4];
#pragma unroll
    for (int kt = 0; kt < 4; ++kt)
      b[kt] = *(const uint4*)((const char*)hp + cur * 512 + kt * 64 + lq * 16);

#pragma unroll
    for (int kt = 0; kt < 4; ++kt)
#pragma unroll
      for (int m = 0; m < 8; ++m)
        acc[m >> 1][m & 1] = mf(wA[kt * 8 + m], b[kt], acc[m >> 1][m & 1]);

    // B phase 2: kt 4..7
#pragma unroll
    for (int kt = 0; kt < 4; ++kt)
      b[kt] = *(const uint4*)((const char*)hp + cur * 512 + (kt + 4) * 64 + lq * 16);

    // L2-resident frags for kt6 mt7 + kt7 (same address every step -> L2 hot)
    uint4 gw[GLN];
#pragma unroll
    for (int i = 0; i < GLN; ++i) gw[i] = gwp[(size_t)i * 64];

    // kt4: regs
#pragma unroll
    for (int m = 0; m < 8; ++m)
      acc[m >> 1][m & 1] = mf(wA[32 + m], b[0], acc[m >> 1][m & 1]);
    // kt5: LDS frags 0..7
#pragma unroll
    for (int m = 0; m < 8; ++m) {
      uint4 la = AL[w][m][lane];
      acc[m >> 1][m & 1] = mf(la, b[1], acc[m >> 1][m & 1]);
    }
    // kt6: LDS frags 8..14 (mt 0..6) + gw[0] (mt 7)
#pragma unroll
    for (int m = 0; m < 7; ++m) {
      uint4 la = AL[w][8 + m][lane];
      acc[m >> 1][m & 1] = mf(la, b[2], acc[m >> 1][m & 1]);
    }
    acc[3][1] = mf(gw[0], b[2], acc[3][1]);
    // kt7: gw[1..8]
#pragma unroll
    for (int m = 0; m < 8; ++m)
      acc[m >> 1][m & 1] = mf(gw[1 + m], b[3], acc[m >> 1][m & 1]);

    // ---- gate bounce: col-0 lane groups write D rows, every lane reads its output ----
    if ((lane & 15) == 0) {
#pragma unroll
      for (int g = 0; g < 4; ++g)
#pragma unroll
        for (int j = 0; j < 2; ++j)
          *(f32x4*)&gbuf[w][g * 32 + j * 16 + lq * 4] = acc[g][j];
    }
    // same-wave LDS dependency: compiler inserts lgkmcnt
    float gi = gbuf[w][0 * 32 + n] + h2f(xg0);
    float gf = gbuf[w][1 * 32 + n] + h2f(xg1);
    float gg = gbuf[w][2 * 32 + n] + h2f(xg2);
    float go = gbuf[w][3 * 32 + n] + h2f(xg3);
    float iv = sig_(gi), fv = sig_(gf), gv = tanh_(gg), ov = sig_(go);
    creg = fv * creg + iv * gv;
    float h = ov * tanh_(creg);
    if (lane < 32) {
      *pout = h;
      hp[cur ^ 1][32 * w + n] = f2h(h);
    }
    pout += ostr;
    __syncthreads();
    tphys += dstep;
  }
  (void)tphys;
}

// ---------------- host ----------------

extern "C" void kernel_launch(void* const* d_in, const int* in_sizes, int n_in,
                              void* d_out, int out_size, void* d_ws, size_t ws_size,
                              hipStream_t stream) {
  const float* x     = (const float*)d_in[0];
  const float* Wih_f = (const float*)d_in[1];
  const float* Whh_f = (const float*)d_in[2];
  const float* bih_f = (const float*)d_in[3];
  const float* bhh_f = (const float*)d_in[4];
  const float* Wih_b = (const float*)d_in[5];
  const float* Whh_b = (const float*)d_in[6];
  const float* bib_b = (const float*)d_in[7];
  const float* bhh_b = (const float*)d_in[8];
  float* out = (float*)d_out;

  const size_t szW16  = (size_t)NC * KT * 2;            // 2 MiB
  const size_t szBias = (size_t)NC * 4;
  const size_t szWF   = (size_t)2 * 8 * 64 * 64 * 16;   // 1 MiB frag buffer

  int c = 0;
  size_t szA16 = 0, szXp = 0;
  for (int cc = 1; cc <= 16; cc *= 2) {
    size_t a = (size_t)(Bn / cc) * Tn * KT * 2;
    size_t p = (size_t)(Bn / cc) * Tn * NC * 2;
    if (szW16 + szBias + szWF + a + p <= ws_size) { c = cc; szA16 = a; szXp = p; break; }
  }
  if (c == 0) {
    k_bad<<<(out_size + 255) / 256, 256, 0, stream>>>(out, out_size);
    return;
  }

  char* ws = (char*)d_ws;
  ushort* W16   = (ushort*)ws;
  float*  biasc = (float*)(ws + szW16);
  uint4*  WF    = (uint4*)(ws + szW16 + szBias);
  ushort* A16   = (ushort*)(ws + szW16 + szBias + szWF);
  ushort* xp    = (ushort*)(ws + szW16 + szBias + szWF + szA16);

  {
    long n4 = (long)NC * (KT / 4);
    k_prep_w<<<(int)((n4 + 255) / 256), 256, 0, stream>>>(Wih_f, Wih_b, bih_f, bhh_f,
                                                          bib_b, bhh_b, W16, biasc);
  }
  k_prep_whh<<<(2 * 8 * 64 * 64) / 256, 256, 0, stream>>>(Whh_f, Whh_b, WF);

  const int sizeB = Bn / c;
  for (int cb = 0; cb < c; ++cb) {
    const int b_base = cb * sizeB;
    {
      long nquad = (long)sizeB * Tn * KT / 4;
      k_prep_a<<<(int)((nquad + 255) / 256), 256, 0, stream>>>(
          x + (size_t)b_base * Tn * Dn, A16, nquad);
    }
    k_gemm<<<dim3(sizeB * 8 * 16), dim3(256), 0, stream>>>(A16, W16, biasc, xp);
    k_lstm<<<dim3(2 * sizeB), dim3(512), 0, stream>>>(WF, xp, out, b_base);
  }
}

// Round 7
// 1880.635 us; speedup vs baseline: 1.8110x; 1.1046x over previous
//
#include <hip/hip_runtime.h>
#include <cstdint>
#include <cstddef>

// Bidirectional LSTM  B=32 T=1024 D=512 H=256 (torch gate order i,f,g,o), fp32 in/out.
//
// Phase 1: xp[m][n] = sum_k x16[m][k] * W16[n][k] + bias[n]  (fp16 MFMA GEMM, xp fp16)
// Phase 2: MFMA recurrence. One block per (dir,batch) chain, 512 threads (8 waves).
//   Wave w owns outputs [32w,32w+32): M-tiles {g*16+2w+j}. 64 A-frags per wave:
//   45 in registers (unified VGPR+AGPR, MFMA reads A from AGPR natively) and
//   19 in LDS -- NO in-loop global/L2 weight traffic. B-frag: all 16 cols load the
//   same h chunk. Activation via 4KB LDS bounce, 1 barrier/step.

typedef unsigned int   uint;
typedef unsigned short ushort;

constexpr int Tn = 1024;
constexpr int Bn = 32;
constexpr int Dn = 512;
constexpr int Hn = 256;
constexpr int NC = 2048;          // 2 dirs * 4H
constexpr int KT = 512;           // K of the input projection

constexpr int AR  = 45;           // reg-resident A frags per wave (fidx 0..44)
constexpr int ALN = 19;           // LDS-resident A frags per wave (fidx 45..63)

typedef _Float16 half8  __attribute__((ext_vector_type(8)));
typedef float    f32x4  __attribute__((ext_vector_type(4)));

__device__ __forceinline__ ushort f2h(float f) {
  _Float16 h = (_Float16)f;               // RNE
  return __builtin_bit_cast(ushort, h);
}
__device__ __forceinline__ float h2f(ushort s) {
  return (float)__builtin_bit_cast(_Float16, s);
}
__device__ __forceinline__ uint packh(float a, float b) {
  return (uint)f2h(a) | ((uint)f2h(b) << 16);
}
__device__ __forceinline__ f32x4 mf(uint4 a, uint4 b, f32x4 c) {
  return __builtin_amdgcn_mfma_f32_16x16x32_f16(
      __builtin_bit_cast(half8, a), __builtin_bit_cast(half8, b), c, 0, 0, 0);
}

__device__ __forceinline__ float sig_(float x) {
  x = fminf(fmaxf(x, -30.f), 30.f);
  return 1.f / (1.f + __expf(-x));
}
__device__ __forceinline__ float tanh_(float x) {
  x = fminf(fmaxf(x, -15.f), 15.f);
  float e = __expf(2.f * x);
  return (e - 1.f) / (e + 1.f);
}

// ---------------- prep kernels ----------------

__global__ void k_prep_a(const float* __restrict__ x, ushort* __restrict__ a16, long nquad) {
  long i4 = (long)blockIdx.x * blockDim.x + threadIdx.x;
  if (i4 >= nquad) return;
  const float4 v = ((const float4*)x)[i4];
  ushort4 o;
  o.x = f2h(v.x); o.y = f2h(v.y); o.z = f2h(v.z); o.w = f2h(v.w);
  ((ushort4*)a16)[i4] = o;
}

__global__ void k_prep_w(const float* __restrict__ wf, const float* __restrict__ wb,
                         const float* __restrict__ bf1, const float* __restrict__ bf2,
                         const float* __restrict__ bb1, const float* __restrict__ bb2,
                         ushort* __restrict__ w16, float* __restrict__ biasc) {
  long i4 = (long)blockIdx.x * blockDim.x + threadIdx.x;
  if (i4 >= (long)NC * (KT / 4)) return;
  int n = (int)(i4 >> 7);
  int k4 = (int)(i4 & 127);
  int dir = n >> 10, g = n & 1023;
  const float* w = dir ? wb : wf;
  const float4 v = ((const float4*)(w + (size_t)g * Dn))[k4];
  ushort4 o;
  o.x = f2h(v.x); o.y = f2h(v.y); o.z = f2h(v.z); o.w = f2h(v.w);
  ((ushort4*)w16)[i4] = o;
  if (k4 == 0) biasc[n] = dir ? (bb1[g] + bb2[g]) : (bf1[g] + bf2[g]);
}

// Whh -> MFMA A-fragment layout. WF[dir][wave][fidx][lane] (uint4 = half8).
// fidx = kt*8 + (g*2+j); tile = g*16 + 2*w + j; row = tile*16 + (lane&15);
// k = kt*32 + (lane>>4)*8 .. +7.
__global__ void k_prep_whh(const float* __restrict__ whhF, const float* __restrict__ whhB,
                           uint4* __restrict__ WF) {
  int t = blockIdx.x * blockDim.x + threadIdx.x;   // 0 .. 2*8*64*64-1
  if (t >= 2 * 8 * 64 * 64) return;
  int lane = t & 63;
  int fidx = (t >> 6) & 63;
  int w    = (t >> 12) & 7;
  int dir  = t >> 15;
  int kt = fidx >> 3, mi = fidx & 7;
  int g = mi >> 1, j = mi & 1;
  int row = (g * 16 + 2 * w + j) * 16 + (lane & 15);
  int kb  = kt * 32 + (lane >> 4) * 8;
  const float* whh = dir ? whhB : whhF;
  const float4* s = (const float4*)(whh + (size_t)row * Hn + kb);
  float4 v0 = s[0], v1 = s[1];
  WF[t] = (uint4){ packh(v0.x, v0.y), packh(v0.z, v0.w),
                   packh(v1.x, v1.y), packh(v1.z, v1.w) };
}

__global__ void k_bad(float* __restrict__ out, int n) {
  int i = blockIdx.x * blockDim.x + threadIdx.x;
  if (i < n) out[i] = 54321.f;
}

// ---------------- phase 1: fp16 MFMA GEMM ----------------

__device__ __forceinline__ void gload_lds16(const void* g, void* l) {
  __builtin_amdgcn_global_load_lds((const __attribute__((address_space(1))) void*)g,
                                   (__attribute__((address_space(3))) void*)l, 16, 0, 0);
}

__global__ __launch_bounds__(256) void k_gemm(const ushort* __restrict__ A,
                                              const ushort* __restrict__ W,
                                              const float* __restrict__ biasc,
                                              ushort* __restrict__ xp) {
  __shared__ __align__(16) ushort As[128 * 32];
  __shared__ __align__(16) ushort Bs[128 * 32];
  const int bid = blockIdx.x;
  const int m0 = (bid >> 4) * 128;
  const int n0 = (bid & 15) * 128;
  const int tid = threadIdx.x;
  const int wid = tid >> 6, lane = tid & 63;
  const int wr = wid >> 1, wcq = wid & 1;
  const int l16 = lane & 15, lq = lane >> 4;

  f32x4 acc[4][4] = {};

  for (int kt = 0; kt < KT; kt += 32) {
    __syncthreads();
#pragma unroll
    for (int i = 0; i < 2; ++i) {
      int ch = wid * 2 + i;
      int p = ch * 64 + lane;
      int r = p >> 2, gp = p & 3;
      int gs = gp ^ ((r >> 1) & 3);
      gload_lds16(A + (size_t)(m0 + r) * KT + kt + gs * 8, (char*)As + ch * 1024);
      gload_lds16(W + (size_t)(n0 + r) * KT + kt + gs * 8, (char*)Bs + ch * 1024);
    }
    __syncthreads();

    half8 af[4], bfr[4];
#pragma unroll
    for (int mfi = 0; mfi < 4; ++mfi) {
      int row = wr * 64 + mfi * 16 + l16;
      int g = lq ^ ((row >> 1) & 3);
      af[mfi] = *(const half8*)((const char*)As + row * 64 + g * 16);
    }
#pragma unroll
    for (int nf = 0; nf < 4; ++nf) {
      int row = wcq * 64 + nf * 16 + l16;
      int g = lq ^ ((row >> 1) & 3);
      bfr[nf] = *(const half8*)((const char*)Bs + row * 64 + g * 16);
    }
#pragma unroll
    for (int mfi = 0; mfi < 4; ++mfi)
#pragma unroll
      for (int nf = 0; nf < 4; ++nf)
        acc[mfi][nf] = __builtin_amdgcn_mfma_f32_16x16x32_f16(af[mfi], bfr[nf], acc[mfi][nf], 0, 0, 0);
  }

#pragma unroll
  for (int nf = 0; nf < 4; ++nf) {
    int col = n0 + wcq * 64 + nf * 16 + l16;
    float bv = biasc[col];
#pragma unroll
    for (int mfi = 0; mfi < 4; ++mfi) {
      int rbase = m0 + wr * 64 + mfi * 16 + lq * 4;
#pragma unroll
      for (int i = 0; i < 4; ++i)
        xp[(size_t)(rbase + i) * NC + col] = f2h(acc[mfi][nf][i] + bv);
    }
  }
}

// ---------------- phase 2: MFMA recurrence ----------------

__global__ __launch_bounds__(512, 2) void k_lstm(const uint4* __restrict__ WF,
                                                 const ushort* __restrict__ xp,
                                                 float* __restrict__ out,
                                                 int b_base) {
  const int dir = blockIdx.x & 1;
  const int bl  = blockIdx.x >> 1;
  const int tid = threadIdx.x;
  const int w    = tid >> 6;
  const int lane = tid & 63;
  const int lq   = lane >> 4;      // k-chunk / row-quad
  const int n    = lane & 31;      // this lane's output within the wave (2x redundant)

  __shared__ __align__(16) uint4  AL[8][ALN][64];   // 152 KB LDS A-frags
  __shared__ float  gbuf[8][128];                   // 4 KB gate bounce
  __shared__ ushort hp[2][256];                     // 1 KB h double buffer

  // ---- persistent weights: 45 frags in regs (VGPR+AGPR), 19 in LDS ----
  const uint4* wfb = WF + (size_t)((dir * 8 + w) * 64) * 64 + lane;
  uint4 wA[AR];
#pragma unroll
  for (int f = 0; f < AR; ++f) wA[f] = wfb[(size_t)f * 64];
#pragma unroll
  for (int s = 0; s < ALN; ++s) AL[w][s][lane] = wfb[(size_t)(AR + s) * 64];

  if (tid < 256) { hp[0][tid] = 0; hp[1][tid] = 0; }
  float creg = 0.f;
  __syncthreads();

  const int dstep = dir ? -1 : 1;
  const ptrdiff_t xstr = (ptrdiff_t)dstep * NC;
  const ptrdiff_t ostr = (ptrdiff_t)dstep * 512;
  const int t0 = dir ? (Tn - 1) : 0;
  const ushort* px = xp + (size_t)(bl * Tn + t0) * NC + dir * 1024 + 32 * w + n;
  float* pout = out + (size_t)((b_base + bl) * Tn + t0) * 512 + dir * 256 + 32 * w + n;

#pragma unroll 1
  for (int t = 0; t < Tn; ++t) {
    const int cur = t & 1;
    // xp for this lane's output (consumed at step end; latency hidden under MFMA)
    ushort xg0 = px[0], xg1 = px[256], xg2 = px[512], xg3 = px[768];
    if (t + 1 < Tn) px += xstr;

    f32x4 acc[4][2];
#pragma unroll
    for (int g = 0; g < 4; ++g)
#pragma unroll
      for (int j = 0; j < 2; ++j) acc[g][j] = (f32x4){0.f, 0.f, 0.f, 0.f};

    // B phase 1: kt 0..3 (every lane loads the same h chunk -> all cols equal)
    uint4 b[4];
#pragma unroll
    for (int kt = 0; kt < 4; ++kt)
      b[kt] = *(const uint4*)((const char*)hp + cur * 512 + kt * 64 + lq * 16);

#pragma unroll
    for (int kt = 0; kt < 4; ++kt)
#pragma unroll
      for (int m = 0; m < 8; ++m)
        acc[m >> 1][m & 1] = mf(wA[kt * 8 + m], b[kt], acc[m >> 1][m & 1]);

    // B phase 2: kt 4..7
#pragma unroll
    for (int kt = 0; kt < 4; ++kt)
      b[kt] = *(const uint4*)((const char*)hp + cur * 512 + (kt + 4) * 64 + lq * 16);

    // kt4: regs wA[32..39]
#pragma unroll
    for (int m = 0; m < 8; ++m)
      acc[m >> 1][m & 1] = mf(wA[32 + m], b[0], acc[m >> 1][m & 1]);
    // kt5: m 0..4 regs wA[40..44], m 5..7 LDS AL[0..2]
#pragma unroll
    for (int m = 0; m < 5; ++m)
      acc[m >> 1][m & 1] = mf(wA[40 + m], b[1], acc[m >> 1][m & 1]);
#pragma unroll
    for (int m = 5; m < 8; ++m) {
      uint4 la = AL[w][m - 5][lane];
      acc[m >> 1][m & 1] = mf(la, b[1], acc[m >> 1][m & 1]);
    }
    // kt6: LDS AL[3..10]
#pragma unroll
    for (int m = 0; m < 8; ++m) {
      uint4 la = AL[w][3 + m][lane];
      acc[m >> 1][m & 1] = mf(la, b[2], acc[m >> 1][m & 1]);
    }
    // kt7: LDS AL[11..18]
#pragma unroll
    for (int m = 0; m < 8; ++m) {
      uint4 la = AL[w][11 + m][lane];
      acc[m >> 1][m & 1] = mf(la, b[3], acc[m >> 1][m & 1]);
    }

    // ---- gate bounce: col-0 lane groups write D rows, every lane reads its output ----
    if ((lane & 15) == 0) {
#pragma unroll
      for (int g = 0; g < 4; ++g)
#pragma unroll
        for (int j = 0; j < 2; ++j)
          *(f32x4*)&gbuf[w][g * 32 + j * 16 + lq * 4] = acc[g][j];
    }
    // same-wave LDS dependency: compiler inserts lgkmcnt
    float gi = gbuf[w][0 * 32 + n] + h2f(xg0);
    float gf = gbuf[w][1 * 32 + n] + h2f(xg1);
    float gg = gbuf[w][2 * 32 + n] + h2f(xg2);
    float go = gbuf[w][3 * 32 + n] + h2f(xg3);
    float iv = sig_(gi), fv = sig_(gf), gv = tanh_(gg), ov = sig_(go);
    creg = fv * creg + iv * gv;
    float h = ov * tanh_(creg);
    if (lane < 32) {
      *pout = h;
      hp[cur ^ 1][32 * w + n] = f2h(h);
    }
    pout += ostr;
    __syncthreads();
  }
}

// ---------------- host ----------------

extern "C" void kernel_launch(void* const* d_in, const int* in_sizes, int n_in,
                              void* d_out, int out_size, void* d_ws, size_t ws_size,
                              hipStream_t stream) {
  const float* x     = (const float*)d_in[0];
  const float* Wih_f = (const float*)d_in[1];
  const float* Whh_f = (const float*)d_in[2];
  const float* bih_f = (const float*)d_in[3];
  const float* bhh_f = (const float*)d_in[4];
  const float* Wih_b = (const float*)d_in[5];
  const float* Whh_b = (const float*)d_in[6];
  const float* bib_b = (const float*)d_in[7];
  const float* bhh_b = (const float*)d_in[8];
  float* out = (float*)d_out;

  const size_t szW16  = (size_t)NC * KT * 2;            // 2 MiB
  const size_t szBias = (size_t)NC * 4;
  const size_t szWF   = (size_t)2 * 8 * 64 * 64 * 16;   // 1 MiB frag buffer

  int c = 0;
  size_t szA16 = 0, szXp = 0;
  for (int cc = 1; cc <= 16; cc *= 2) {
    size_t a = (size_t)(Bn / cc) * Tn * KT * 2;
    size_t p = (size_t)(Bn / cc) * Tn * NC * 2;
    if (szW16 + szBias + szWF + a + p <= ws_size) { c = cc; szA16 = a; szXp = p; break; }
  }
  if (c == 0) {
    k_bad<<<(out_size + 255) / 256, 256, 0, stream>>>(out, out_size);
    return;
  }

  char* ws = (char*)d_ws;
  ushort* W16   = (ushort*)ws;
  float*  biasc = (float*)(ws + szW16);
  uint4*  WF    = (uint4*)(ws + szW16 + szBias);
  ushort* A16   = (ushort*)(ws + szW16 + szBias + szWF);
  ushort* xp    = (ushort*)(ws + szW16 + szBias + szWF + szA16);

  {
    long n4 = (long)NC * (KT / 4);
    k_prep_w<<<(int)((n4 + 255) / 256), 256, 0, stream>>>(Wih_f, Wih_b, bih_f, bhh_f,
                                                          bib_b, bhh_b, W16, biasc);
  }
  k_prep_whh<<<(2 * 8 * 64 * 64) / 256, 256, 0, stream>>>(Whh_f, Whh_b, WF);

  const int sizeB = Bn / c;
  for (int cb = 0; cb < c; ++cb) {
    const int b_base = cb * sizeB;
    {
      long nquad = (long)sizeB * Tn * KT / 4;
      k_prep_a<<<(int)((nquad + 255) / 256), 256, 0, stream>>>(
          x + (size_t)b_base * Tn * Dn, A16, nquad);
    }
    k_gemm<<<dim3(sizeB * 8 * 16), dim3(256), 0, stream>>>(A16, W16, biasc, xp);
    k_lstm<<<dim3(2 * sizeB), dim3(512), 0, stream>>>(WF, xp, out, b_base);
  }
}